// Round 10
// baseline (1069.840 us; speedup 1.0000x reference)
//
#include <hip/hip_runtime.h>

#define N_NODES 100000
#define N_EDGES 1600000
#define D 64
#define XROW 64                                   // ab row: x only (bf16)
#define WROW 128                                  // Wb row: [rel_W | root_W]
#define NB1 196                                   // windows = dst>>9 (512 nodes each)
#define WCAP 9024                                 // per-window dense capacity (mean 8192, sigma 91, +9 sigma)
#define SLOTN 64                                  // per-node LDS slots (P(deg>64)*N ~ 1e-15)
#define ASH 72                                    // a_sh row stride (bf16): 144B, 16B-aligned
#define P1BLK 2048                                // part1v2 grid
#define P1STRIDE (P1BLK * 256)

typedef __attribute__((ext_vector_type(8))) short bf16x8;
typedef __attribute__((ext_vector_type(4))) float f32x4;

__device__ __forceinline__ unsigned short f2bf(float f) {
    unsigned bits = __float_as_uint(f);
    bits += 0x7FFF + ((bits >> 16) & 1);          // RNE
    return (unsigned short)(bits >> 16);
}

// ---------------------------------------------------------------- part1v2: dense-window binning + staging
// No LDS histogram/flush: per edge one global returning-atomic on 196 window
// cursors (chains ~8200/counter run parallel across L2 channels) + one dense
// write into the window's contiguous region (6.9MB hot footprint -> L2-resident
// -> full-line writeback). Produces contiguous per-window edge lists, which is
// what part2 existed to approximate -> part2 deleted.
__global__ __launch_bounds__(256) void part1v2(
    const float* __restrict__ x, const float* __restrict__ rel_W,
    const float* __restrict__ root_W, const int* __restrict__ row,
    const int* __restrict__ col,
    unsigned short* __restrict__ ab, unsigned short* __restrict__ Wb,
    int* __restrict__ wcur, unsigned* __restrict__ edgesD)
{
    const int t = blockIdx.x * 256 + threadIdx.x;

    for (int e = t; e < N_EDGES; e += P1STRIDE) { // ~3 edges/thread
        int d = col[e];
        int wnd = d >> 9;
        int ticket = atomicAdd(&wcur[wnd], 1);
        if (ticket < WCAP)                        // overflow guard (P ~ 1e-15)
            edgesD[(size_t)wnd * WCAP + ticket] =
                ((unsigned)(d & 511) << 17) | (unsigned)row[e];
    }

    // ---- staging x -> ab (bf16, 64-wide rows), grid-stride
    for (int i = t; i < N_NODES * 8; i += P1STRIDE) {
        int nrow = i >> 3, g = i & 7;
        const float4* xf = (const float4*)(x + (size_t)nrow * D + g * 8);
        float4 a = xf[0], b = xf[1];
        unsigned short u[8];
        u[0] = f2bf(a.x); u[1] = f2bf(a.y); u[2] = f2bf(a.z); u[3] = f2bf(a.w);
        u[4] = f2bf(b.x); u[5] = f2bf(b.y); u[6] = f2bf(b.z); u[7] = f2bf(b.w);
        *reinterpret_cast<uint4*>(ab + (size_t)nrow * XROW + g * 8) =
            *reinterpret_cast<const uint4*>(u);
    }
    if (t < 1024) {                               // Wb row j = [rel_W j | root_W j]
        int j = t >> 4, g = t & 15;
        const float* src = (g < 8) ? (rel_W + j * 64 + g * 8) : (root_W + j * 64 + (g - 8) * 8);
        unsigned short u[8];
        #pragma unroll
        for (int i = 0; i < 8; ++i) u[i] = f2bf(src[i]);
        *reinterpret_cast<uint4*>(Wb + j * WROW + g * 8) = *reinterpret_cast<const uint4*>(u);
    }
}

// ---------------------------------------------------------------- agg_gemm: filter + gather (r9 core) + GEMM
// Block = 16 nodes (r9-proven shape). Filter: scan the window's dense edge list
// (coalesced, L2-hot across 32 sibling blocks -> XCD swizzle co-locates them),
// keep this block's ~256 edges, scatter into 16x64 LDS slots. Then the r9
// paired gather (8 uint2 loads in flight) with indices from LDS, and the
// fused 16x64x128 MFMA + bias + relu.
__global__ __launch_bounds__(256) void agg_gemm(
    const unsigned short* __restrict__ ab, const unsigned* __restrict__ edgesD,
    const int* __restrict__ wcur, const float* __restrict__ adj_norm,
    const unsigned short* __restrict__ Wb, const float* __restrict__ root_b,
    float* __restrict__ out)
{
    __shared__ int eLs[16 * SLOTN];               // 4 KB
    __shared__ unsigned short a_sh[16 * ASH];     // 2.3 KB
    __shared__ int cnt[16];
    const int tid = threadIdx.x;

    // bijective XCD swizzle (m204): window's 32 sibling blocks -> one XCD
    const int nwg = N_NODES / 16, qq = nwg / 8, rr = nwg % 8;   // 6250, 781, 2
    const int o = blockIdx.x, xcd = o & 7;
    const int b = (xcd < rr ? xcd * (qq + 1) : rr * (qq + 1) + (xcd - rr) * qq) + (o >> 3);

    const int wv = tid >> 6, lane = tid & 63;
    const int q = lane >> 4, sub = lane & 15;
    const int n0 = b * 16;
    const int wnd = n0 >> 9;
    const int grp = (n0 >> 4) & 31;               // which 16-node group of the window

    if (tid < 16) cnt[tid] = 0;
    __syncthreads();

    // ---- filter + slot-scatter
    int wtot = wcur[wnd]; if (wtot > WCAP) wtot = WCAP;
    const unsigned* __restrict__ src = edgesD + (size_t)wnd * WCAP;
    for (int i = tid; i < wtot; i += 256) {
        unsigned e = src[i];
        int dl = (int)(e >> 17);                  // 0..511 within window
        if ((dl >> 4) == grp) {
            int ln = dl & 15;
            int r = atomicAdd(&cnt[ln], 1);
            if (r < SLOTN) eLs[ln * SLOTN + r] = (int)(e & 0x1FFFF);
        }
    }
    __syncthreads();

    // ---- paired gather (r9-proven): wave wv -> local nodes wv*4..+4 as 2 pairs
    const unsigned short* __restrict__ xh = ab + sub * 4;

    #pragma unroll
    for (int t = 0; t < 2; ++t) {
        const int lnA = wv * 4 + t * 2, lnB = lnA + 1;
        const int gnA = n0 + lnA, gnB = n0 + lnB;
        int dgA = cnt[lnA]; if (dgA > SLOTN) dgA = SLOTN;
        int dgB = cnt[lnB]; if (dgB > SLOTN) dgB = SLOTN;

        float a0A = 0.f, a1A = 0.f, a2A = 0.f, a3A = 0.f;
        float a0B = 0.f, a1B = 0.f, a2B = 0.f, a3B = 0.f;
        int idxA = (lane < dgA) ? eLs[lnA * SLOTN + lane] : 0;
        int idxB = (lane < dgB) ? eLs[lnB * SLOTN + lane] : 0;

        const int dgM = dgA > dgB ? dgA : dgB;
        for (int eb = 0; eb < dgM; eb += 16) {    // guarded 16-edge step per node
            const int e = eb + q;
            bool kA0 = e < dgA, kA1 = e + 4 < dgA, kA2 = e + 8 < dgA, kA3 = e + 12 < dgA;
            bool kB0 = e < dgB, kB1 = e + 4 < dgB, kB2 = e + 8 < dgB, kB3 = e + 12 < dgB;
            int iA0 = __shfl(idxA, e);      int iA1 = __shfl(idxA, e + 4);
            int iA2 = __shfl(idxA, e + 8);  int iA3 = __shfl(idxA, e + 12);
            int iB0 = __shfl(idxB, e);      int iB1 = __shfl(idxB, e + 4);
            int iB2 = __shfl(idxB, e + 8);  int iB3 = __shfl(idxB, e + 12);
            uint2 uA0 = *reinterpret_cast<const uint2*>(xh + (size_t)iA0 * XROW);
            uint2 uA1 = *reinterpret_cast<const uint2*>(xh + (size_t)iA1 * XROW);
            uint2 uA2 = *reinterpret_cast<const uint2*>(xh + (size_t)iA2 * XROW);
            uint2 uA3 = *reinterpret_cast<const uint2*>(xh + (size_t)iA3 * XROW);
            uint2 uB0 = *reinterpret_cast<const uint2*>(xh + (size_t)iB0 * XROW);
            uint2 uB1 = *reinterpret_cast<const uint2*>(xh + (size_t)iB1 * XROW);
            uint2 uB2 = *reinterpret_cast<const uint2*>(xh + (size_t)iB2 * XROW);
            uint2 uB3 = *reinterpret_cast<const uint2*>(xh + (size_t)iB3 * XROW);
            if (!kA0) { uA0.x = 0u; uA0.y = 0u; }
            if (!kA1) { uA1.x = 0u; uA1.y = 0u; }
            if (!kA2) { uA2.x = 0u; uA2.y = 0u; }
            if (!kA3) { uA3.x = 0u; uA3.y = 0u; }
            if (!kB0) { uB0.x = 0u; uB0.y = 0u; }
            if (!kB1) { uB1.x = 0u; uB1.y = 0u; }
            if (!kB2) { uB2.x = 0u; uB2.y = 0u; }
            if (!kB3) { uB3.x = 0u; uB3.y = 0u; }
            a0A += __uint_as_float(uA0.x << 16) + __uint_as_float(uA1.x << 16)
                 + __uint_as_float(uA2.x << 16) + __uint_as_float(uA3.x << 16);
            a1A += __uint_as_float(uA0.x & 0xffff0000u) + __uint_as_float(uA1.x & 0xffff0000u)
                 + __uint_as_float(uA2.x & 0xffff0000u) + __uint_as_float(uA3.x & 0xffff0000u);
            a2A += __uint_as_float(uA0.y << 16) + __uint_as_float(uA1.y << 16)
                 + __uint_as_float(uA2.y << 16) + __uint_as_float(uA3.y << 16);
            a3A += __uint_as_float(uA0.y & 0xffff0000u) + __uint_as_float(uA1.y & 0xffff0000u)
                 + __uint_as_float(uA2.y & 0xffff0000u) + __uint_as_float(uA3.y & 0xffff0000u);
            a0B += __uint_as_float(uB0.x << 16) + __uint_as_float(uB1.x << 16)
                 + __uint_as_float(uB2.x << 16) + __uint_as_float(uB3.x << 16);
            a1B += __uint_as_float(uB0.x & 0xffff0000u) + __uint_as_float(uB1.x & 0xffff0000u)
                 + __uint_as_float(uB2.x & 0xffff0000u) + __uint_as_float(uB3.x & 0xffff0000u);
            a2B += __uint_as_float(uB0.y << 16) + __uint_as_float(uB1.y << 16)
                 + __uint_as_float(uB2.y << 16) + __uint_as_float(uB3.y << 16);
            a3B += __uint_as_float(uB0.y & 0xffff0000u) + __uint_as_float(uB1.y & 0xffff0000u)
                 + __uint_as_float(uB2.y & 0xffff0000u) + __uint_as_float(uB3.y & 0xffff0000u);
        }

        a0A += __shfl_xor(a0A, 16, 64); a0A += __shfl_xor(a0A, 32, 64);
        a1A += __shfl_xor(a1A, 16, 64); a1A += __shfl_xor(a1A, 32, 64);
        a2A += __shfl_xor(a2A, 16, 64); a2A += __shfl_xor(a2A, 32, 64);
        a3A += __shfl_xor(a3A, 16, 64); a3A += __shfl_xor(a3A, 32, 64);
        a0B += __shfl_xor(a0B, 16, 64); a0B += __shfl_xor(a0B, 32, 64);
        a1B += __shfl_xor(a1B, 16, 64); a1B += __shfl_xor(a1B, 32, 64);
        a2B += __shfl_xor(a2B, 16, 64); a2B += __shfl_xor(a2B, 32, 64);
        a3B += __shfl_xor(a3B, 16, 64); a3B += __shfl_xor(a3B, 32, 64);

        if (q == 0) {                             // lane sub writes node A from own regs
            float invA = 1.0f / adj_norm[gnA];
            uint2 pA;
            pA.x = (unsigned)f2bf(a0A * invA) | ((unsigned)f2bf(a1A * invA) << 16);
            pA.y = (unsigned)f2bf(a2A * invA) | ((unsigned)f2bf(a3A * invA) << 16);
            *reinterpret_cast<uint2*>(a_sh + lnA * ASH + sub * 4) = pA;
        } else if (q == 1) {                      // lane 16+sub writes node B from own regs
            float invB = 1.0f / adj_norm[gnB];
            uint2 pB;
            pB.x = (unsigned)f2bf(a0B * invB) | ((unsigned)f2bf(a1B * invB) << 16);
            pB.y = (unsigned)f2bf(a2B * invB) | ((unsigned)f2bf(a3B * invB) << 16);
            *reinterpret_cast<uint2*>(a_sh + lnB * ASH + sub * 4) = pB;
        }
    }
    __syncthreads();

    // ---- GEMM 16x64x128: M rows = block's 16 nodes, wave wv -> N-tile wv (r7/r9-proven)
    const int gnr = n0 + sub;                     // always < N_NODES (exact division)
    bf16x8 afrag[4];
    afrag[0] = *reinterpret_cast<const bf16x8*>(a_sh + sub * ASH + q * 8);
    afrag[1] = *reinterpret_cast<const bf16x8*>(a_sh + sub * ASH + q * 8 + 32);
    afrag[2] = *reinterpret_cast<const bf16x8*>(ab + (size_t)gnr * XROW + q * 8);
    afrag[3] = *reinterpret_cast<const bf16x8*>(ab + (size_t)gnr * XROW + q * 8 + 32);

    f32x4 acc = {0.f, 0.f, 0.f, 0.f};
    #pragma unroll
    for (int kk = 0; kk < 4; ++kk) {
        bf16x8 bfrag = *reinterpret_cast<const bf16x8*>(
            Wb + (wv * 16 + sub) * WROW + q * 8 + kk * 32);
        acc = __builtin_amdgcn_mfma_f32_16x16x32_bf16(afrag[kk], bfrag, acc, 0, 0, 0);
    }

    const int j = wv * 16 + sub;
    const float bias = root_b[j];
    #pragma unroll
    for (int r = 0; r < 4; ++r) {
        int node = n0 + q * 4 + r;
        out[(size_t)node * D + j] = fmaxf(acc[r] + bias, 0.0f);
    }
}

// ---------------------------------------------------------------- launch (memset + 2 dispatches)
extern "C" void kernel_launch(void* const* d_in, const int* in_sizes, int n_in,
                              void* d_out, int out_size, void* d_ws, size_t ws_size,
                              hipStream_t stream)
{
    const float* x        = (const float*)d_in[0];
    const int*   row      = (const int*)d_in[1];
    const int*   col      = (const int*)d_in[2];
    const float* adj_norm = (const float*)d_in[4];
    const float* root_W   = (const float*)d_in[5];
    const float* root_b   = (const float*)d_in[6];
    const float* rel_W    = (const float*)d_in[7];
    float* out = (float*)d_out;

    char* ws = (char*)d_ws;
    unsigned short* ab = (unsigned short*)ws;  ws += (size_t)N_NODES * XROW * 2;   // 12.8 MB
    unsigned short* Wb = (unsigned short*)ws;  ws += 64 * WROW * 2;                // 16 KB
    int* wcur          = (int*)ws;             ws += ((size_t)NB1 * 4 + 255) / 256 * 256;
    unsigned* edgesD   = (unsigned*)ws;                                            // 196*9024*4 = 7.1 MB

    hipMemsetAsync(wcur, 0, NB1 * sizeof(int), stream);

    part1v2<<<P1BLK, 256, 0, stream>>>(x, rel_W, root_W, row, col, ab, Wb, wcur, edgesD);
    agg_gemm<<<N_NODES / 16, 256, 0, stream>>>(ab, edgesD, wcur, adj_norm, Wb, root_b, out);
}

// Round 12
// 316.649 us; speedup vs baseline: 3.3786x; 3.3786x over previous
//
#include <hip/hip_runtime.h>

#define N_NODES 100000
#define N_EDGES 1600000
#define D 64
#define XROW 64                                   // ab row: x only (bf16)
#define WROW 128                                  // Wb row: [rel_W | root_W]
#define NB1 196                                   // windows = dst>>9 (512 nodes each)
#define CAP 96                                    // per-(block,window) run capacity (mean 41.9, +8.4 sigma)
#define CHUNK1 8192                               // edges per part1 block (big runs -> low fragmentation)
#define NBLK1 196
#define WCAP 9024                                 // dense per-window capacity (mean 8192, sigma 90, +9.2 sigma)
#define SLOTN 64                                  // per-node edge slots (P(deg>64)*N ~ 1e-15)
#define ASH 72                                    // a_sh row stride (bf16): 144B, 16B-aligned

typedef __attribute__((ext_vector_type(8))) short bf16x8;
typedef __attribute__((ext_vector_type(4))) float f32x4;

__device__ __forceinline__ unsigned short f2bf(float f) {
    unsigned bits = __float_as_uint(f);
    bits += 0x7FFF + ((bits >> 16) & 1);          // RNE
    return (unsigned short)(bits >> 16);
}

// ---------------------------------------------------------------- part1: LDS binning -> DENSE window lists + staging
// r4-proven binning. Flush change: ONE global atomicAdd per (block,window) run
// (38K total, per-window chain depth 196 staggered -- 50x below r10's measured
// 110ns/op same-address wall at depth 8163) reserves a contiguous span in the
// window's dense region. Kills CAP-padding fragmentation for the consumer.
__global__ __launch_bounds__(1024) void part1(
    const float* __restrict__ x, const float* __restrict__ rel_W,
    const float* __restrict__ root_W, const int* __restrict__ row,
    const int* __restrict__ col,
    unsigned short* __restrict__ ab, unsigned short* __restrict__ Wb,
    int* __restrict__ wcur, unsigned* __restrict__ edgesD)
{
    __shared__ unsigned eL[NB1 * CAP];            // 75.3 KB (static >64KB proven r4)
    __shared__ int cntL[NB1];
    const int tid = threadIdx.x;
    const int blk = blockIdx.x;

    for (int k = tid; k < NB1; k += 1024) cntL[k] = 0;
    __syncthreads();

    const int base = blk * CHUNK1;
    #pragma unroll
    for (int it = 0; it < CHUNK1 / 1024; ++it) {
        int e = base + it * 1024 + tid;
        if (e < N_EDGES) {
            int d = col[e];
            int bk = d >> 9;
            int r = atomicAdd(&cntL[bk], 1);
            if (r < CAP) eL[bk * CAP + r] = ((unsigned)(d & 511) << 17) | (unsigned)row[e];
        }
    }
    __syncthreads();

    const int wv = tid >> 6, lane = tid & 63;     // flush: wave w -> windows w, w+16, ...
    for (int bk = wv; bk < NB1; bk += 16) {
        int c = min(cntL[bk], CAP);               // wave-uniform (same LDS word)
        if (c) {
            int rbase = 0;
            if (lane == 0) rbase = atomicAdd(&wcur[bk], c);
            rbase = __shfl(rbase, 0);
            if (rbase + c > WCAP) c = (rbase < WCAP) ? (WCAP - rbase) : 0;  // P ~ 1e-15
            unsigned* dst = edgesD + (size_t)bk * WCAP + rbase;
            for (int i = lane; i < c; i += 64) dst[i] = eL[bk * CAP + i];
        }
    }

    // ---- staging x -> ab (bf16, 64-wide rows), grid-stride
    const int gt = blk * 1024 + tid;
    for (int t = gt; t < N_NODES * 8; t += NBLK1 * 1024) {
        int nrow = t >> 3, g = t & 7;
        const float4* xf = (const float4*)(x + (size_t)nrow * D + g * 8);
        float4 a = xf[0], b = xf[1];
        unsigned short u[8];
        u[0] = f2bf(a.x); u[1] = f2bf(a.y); u[2] = f2bf(a.z); u[3] = f2bf(a.w);
        u[4] = f2bf(b.x); u[5] = f2bf(b.y); u[6] = f2bf(b.z); u[7] = f2bf(b.w);
        *reinterpret_cast<uint4*>(ab + (size_t)nrow * XROW + g * 8) =
            *reinterpret_cast<const uint4*>(u);
    }
    if (gt < 1024) {                              // Wb row j = [rel_W j | root_W j]
        int j = gt >> 4, g = gt & 15;
        const float* src = (g < 8) ? (rel_W + j * 64 + g * 8) : (root_W + j * 64 + (g - 8) * 8);
        unsigned short u[8];
        #pragma unroll
        for (int i = 0; i < 8; ++i) u[i] = f2bf(src[i]);
        *reinterpret_cast<uint4*>(Wb + j * WROW + g * 8) = *reinterpret_cast<const uint4*>(u);
    }
}

// ---------------------------------------------------------------- part2d: DENSE window list -> per-node CSR
// 392 half-window blocks. Reads are now fully coalesced 100%-lane-efficiency
// streams (8 iters/block) -- no CAP gaps, no fragmented runs. Scattered CSR
// writes stay inside a 64KB L2-hot half-window region (dense writeback, r4-proven).
__global__ __launch_bounds__(1024) void part2d(const unsigned* __restrict__ edgesD,
                                               const int* __restrict__ wcur,
                                               int* __restrict__ deg,
                                               int* __restrict__ edge_src)
{
    __shared__ int cnt[256];
    const int tid = threadIdx.x;
    const int wnd = blockIdx.x >> 1, half = blockIdx.x & 1;
    if (tid < 256) cnt[tid] = 0;
    __syncthreads();

    int wtot = wcur[wnd]; if (wtot > WCAP) wtot = WCAP;
    const unsigned* __restrict__ src = edgesD + (size_t)wnd * WCAP;
    const int nb = wnd * 512;
    for (int i = tid; i < wtot; i += 1024) {
        unsigned e = src[i];
        int dl = (int)(e >> 17);                  // 0..511
        if ((dl >> 8) == half) {
            int r = atomicAdd(&cnt[dl & 255], 1);
            if (r < SLOTN) edge_src[(size_t)(nb + dl) * SLOTN + r] = (int)(e & 0x1FFFF);
        }
    }
    __syncthreads();

    if (tid < 256) {
        int gn = nb + half * 256 + tid;
        if (gn < N_NODES) deg[gn] = cnt[tid];
    }
}

// ---------------------------------------------------------------- agg_gemm: paired gather (8 in flight) + GEMM (r9-proven, 53us)
__global__ __launch_bounds__(256) void agg_gemm(
    const unsigned short* __restrict__ ab, const int* __restrict__ edge_src,
    const int* __restrict__ deg, const float* __restrict__ adj_norm,
    const unsigned short* __restrict__ Wb, const float* __restrict__ root_b,
    float* __restrict__ out)
{
    __shared__ unsigned short a_sh[16 * ASH];     // 2.3 KB
    const int tid = threadIdx.x;
    const int wv = tid >> 6, lane = tid & 63;
    const int q = lane >> 4, sub = lane & 15;
    const int n0 = blockIdx.x * 16;
    const unsigned short* __restrict__ xh = ab + sub * 4;

    #pragma unroll
    for (int t = 0; t < 2; ++t) {
        const int gnA = n0 + wv * 4 + t * 2;
        const int gnB = gnA + 1;
        int dgA = deg[gnA]; if (dgA > SLOTN) dgA = SLOTN;
        int dgB = deg[gnB]; if (dgB > SLOTN) dgB = SLOTN;

        float a0A = 0.f, a1A = 0.f, a2A = 0.f, a3A = 0.f;
        float a0B = 0.f, a1B = 0.f, a2B = 0.f, a3B = 0.f;
        int idxA = (lane < dgA) ? edge_src[(size_t)gnA * SLOTN + lane] : 0;
        int idxB = (lane < dgB) ? edge_src[(size_t)gnB * SLOTN + lane] : 0;

        const int dgM = dgA > dgB ? dgA : dgB;
        for (int eb = 0; eb < dgM; eb += 16) {    // guarded 16-edge step per node
            const int e = eb + q;
            bool kA0 = e < dgA, kA1 = e + 4 < dgA, kA2 = e + 8 < dgA, kA3 = e + 12 < dgA;
            bool kB0 = e < dgB, kB1 = e + 4 < dgB, kB2 = e + 8 < dgB, kB3 = e + 12 < dgB;
            int iA0 = __shfl(idxA, e);      int iA1 = __shfl(idxA, e + 4);
            int iA2 = __shfl(idxA, e + 8);  int iA3 = __shfl(idxA, e + 12);
            int iB0 = __shfl(idxB, e);      int iB1 = __shfl(idxB, e + 4);
            int iB2 = __shfl(idxB, e + 8);  int iB3 = __shfl(idxB, e + 12);
            uint2 uA0 = *reinterpret_cast<const uint2*>(xh + (size_t)iA0 * XROW);
            uint2 uA1 = *reinterpret_cast<const uint2*>(xh + (size_t)iA1 * XROW);
            uint2 uA2 = *reinterpret_cast<const uint2*>(xh + (size_t)iA2 * XROW);
            uint2 uA3 = *reinterpret_cast<const uint2*>(xh + (size_t)iA3 * XROW);
            uint2 uB0 = *reinterpret_cast<const uint2*>(xh + (size_t)iB0 * XROW);
            uint2 uB1 = *reinterpret_cast<const uint2*>(xh + (size_t)iB1 * XROW);
            uint2 uB2 = *reinterpret_cast<const uint2*>(xh + (size_t)iB2 * XROW);
            uint2 uB3 = *reinterpret_cast<const uint2*>(xh + (size_t)iB3 * XROW);
            if (!kA0) { uA0.x = 0u; uA0.y = 0u; }
            if (!kA1) { uA1.x = 0u; uA1.y = 0u; }
            if (!kA2) { uA2.x = 0u; uA2.y = 0u; }
            if (!kA3) { uA3.x = 0u; uA3.y = 0u; }
            if (!kB0) { uB0.x = 0u; uB0.y = 0u; }
            if (!kB1) { uB1.x = 0u; uB1.y = 0u; }
            if (!kB2) { uB2.x = 0u; uB2.y = 0u; }
            if (!kB3) { uB3.x = 0u; uB3.y = 0u; }
            a0A += __uint_as_float(uA0.x << 16) + __uint_as_float(uA1.x << 16)
                 + __uint_as_float(uA2.x << 16) + __uint_as_float(uA3.x << 16);
            a1A += __uint_as_float(uA0.x & 0xffff0000u) + __uint_as_float(uA1.x & 0xffff0000u)
                 + __uint_as_float(uA2.x & 0xffff0000u) + __uint_as_float(uA3.x & 0xffff0000u);
            a2A += __uint_as_float(uA0.y << 16) + __uint_as_float(uA1.y << 16)
                 + __uint_as_float(uA2.y << 16) + __uint_as_float(uA3.y << 16);
            a3A += __uint_as_float(uA0.y & 0xffff0000u) + __uint_as_float(uA1.y & 0xffff0000u)
                 + __uint_as_float(uA2.y & 0xffff0000u) + __uint_as_float(uA3.y & 0xffff0000u);
            a0B += __uint_as_float(uB0.x << 16) + __uint_as_float(uB1.x << 16)
                 + __uint_as_float(uB2.x << 16) + __uint_as_float(uB3.x << 16);
            a1B += __uint_as_float(uB0.x & 0xffff0000u) + __uint_as_float(uB1.x & 0xffff0000u)
                 + __uint_as_float(uB2.x & 0xffff0000u) + __uint_as_float(uB3.x & 0xffff0000u);
            a2B += __uint_as_float(uB0.y << 16) + __uint_as_float(uB1.y << 16)
                 + __uint_as_float(uB2.y << 16) + __uint_as_float(uB3.y << 16);
            a3B += __uint_as_float(uB0.y & 0xffff0000u) + __uint_as_float(uB1.y & 0xffff0000u)
                 + __uint_as_float(uB2.y & 0xffff0000u) + __uint_as_float(uB3.y & 0xffff0000u);
        }

        a0A += __shfl_xor(a0A, 16, 64); a0A += __shfl_xor(a0A, 32, 64);
        a1A += __shfl_xor(a1A, 16, 64); a1A += __shfl_xor(a1A, 32, 64);
        a2A += __shfl_xor(a2A, 16, 64); a2A += __shfl_xor(a2A, 32, 64);
        a3A += __shfl_xor(a3A, 16, 64); a3A += __shfl_xor(a3A, 32, 64);
        a0B += __shfl_xor(a0B, 16, 64); a0B += __shfl_xor(a0B, 32, 64);
        a1B += __shfl_xor(a1B, 16, 64); a1B += __shfl_xor(a1B, 32, 64);
        a2B += __shfl_xor(a2B, 16, 64); a2B += __shfl_xor(a2B, 32, 64);
        a3B += __shfl_xor(a3B, 16, 64); a3B += __shfl_xor(a3B, 32, 64);

        if (q == 0) {                             // lane sub writes node A from own regs
            float invA = 1.0f / adj_norm[gnA];
            uint2 pA;
            pA.x = (unsigned)f2bf(a0A * invA) | ((unsigned)f2bf(a1A * invA) << 16);
            pA.y = (unsigned)f2bf(a2A * invA) | ((unsigned)f2bf(a3A * invA) << 16);
            *reinterpret_cast<uint2*>(a_sh + (wv * 4 + t * 2) * ASH + sub * 4) = pA;
        } else if (q == 1) {                      // lane 16+sub writes node B from own regs
            float invB = 1.0f / adj_norm[gnB];
            uint2 pB;
            pB.x = (unsigned)f2bf(a0B * invB) | ((unsigned)f2bf(a1B * invB) << 16);
            pB.y = (unsigned)f2bf(a2B * invB) | ((unsigned)f2bf(a3B * invB) << 16);
            *reinterpret_cast<uint2*>(a_sh + (wv * 4 + t * 2 + 1) * ASH + sub * 4) = pB;
        }
    }
    __syncthreads();

    // ---- GEMM 16x64x128: M rows = block's 16 nodes, wave wv -> N-tile wv
    const int gnr = n0 + sub;                     // always < N_NODES (exact division)
    bf16x8 afrag[4];
    afrag[0] = *reinterpret_cast<const bf16x8*>(a_sh + sub * ASH + q * 8);
    afrag[1] = *reinterpret_cast<const bf16x8*>(a_sh + sub * ASH + q * 8 + 32);
    afrag[2] = *reinterpret_cast<const bf16x8*>(ab + (size_t)gnr * XROW + q * 8);
    afrag[3] = *reinterpret_cast<const bf16x8*>(ab + (size_t)gnr * XROW + q * 8 + 32);

    f32x4 acc = {0.f, 0.f, 0.f, 0.f};
    #pragma unroll
    for (int kk = 0; kk < 4; ++kk) {
        bf16x8 bfrag = *reinterpret_cast<const bf16x8*>(
            Wb + (wv * 16 + sub) * WROW + q * 8 + kk * 32);
        acc = __builtin_amdgcn_mfma_f32_16x16x32_bf16(afrag[kk], bfrag, acc, 0, 0, 0);
    }

    const int j = wv * 16 + sub;
    const float bias = root_b[j];
    #pragma unroll
    for (int r = 0; r < 4; ++r) {
        int node = n0 + q * 4 + r;
        out[(size_t)node * D + j] = fmaxf(acc[r] + bias, 0.0f);
    }
}

// ---------------------------------------------------------------- launch (memset + 3 dispatches)
extern "C" void kernel_launch(void* const* d_in, const int* in_sizes, int n_in,
                              void* d_out, int out_size, void* d_ws, size_t ws_size,
                              hipStream_t stream)
{
    const float* x        = (const float*)d_in[0];
    const int*   row      = (const int*)d_in[1];
    const int*   col      = (const int*)d_in[2];
    const float* adj_norm = (const float*)d_in[4];
    const float* root_W   = (const float*)d_in[5];
    const float* root_b   = (const float*)d_in[6];
    const float* rel_W    = (const float*)d_in[7];
    float* out = (float*)d_out;

    char* ws = (char*)d_ws;
    unsigned short* ab = (unsigned short*)ws;  ws += (size_t)N_NODES * XROW * 2;   // 12.8 MB
    unsigned short* Wb = (unsigned short*)ws;  ws += 64 * WROW * 2;                // 16 KB
    int* wcur          = (int*)ws;             ws += ((size_t)NB1 * 4 + 255) / 256 * 256;
    int* deg           = (int*)ws;             ws += (size_t)N_NODES * 4;          // 0.4 MB
    unsigned* edgesD   = (unsigned*)ws;        ws += (size_t)NB1 * WCAP * 4;       // 7.1 MB
    int* edge_src      = (int*)ws;                                                 // 25.6 MB

    hipMemsetAsync(wcur, 0, NB1 * sizeof(int), stream);

    part1<<<NBLK1, 1024, 0, stream>>>(x, rel_W, root_W, row, col, ab, Wb, wcur, edgesD);
    part2d<<<NB1 * 2, 1024, 0, stream>>>(edgesD, wcur, deg, edge_src);
    agg_gemm<<<N_NODES / 16, 256, 0, stream>>>(ab, edge_src, deg, adj_norm, Wb, root_b, out);
}

// Round 13
// 193.572 us; speedup vs baseline: 5.5268x; 1.6358x over previous
//
#include <hip/hip_runtime.h>

#define N_NODES 100000
#define N_EDGES 1600000
#define D 64
#define XROW 64                                   // ab row: x only (bf16)
#define WROW 128                                  // Wb row: [rel_W | root_W]
#define NB1 196                                   // windows = dst>>9 (512 nodes each)
#define CAP 96                                    // per-(block,window) run capacity (mean 41.9, +8.4 sigma)
#define CHUNK1 8192                               // edges per part1 block
#define NBLK1 196
#define SLOTN 64                                  // per-node LDS slots (P(deg>64)*N ~ 1e-15)
#define ASH 72                                    // a_sh row stride (bf16): 144B, 16B-aligned
#define NWG 3125                                  // fused grid: 100000/32 exact

typedef __attribute__((ext_vector_type(8))) short bf16x8;
typedef __attribute__((ext_vector_type(4))) float f32x4;

__device__ __forceinline__ unsigned short f2bf(float f) {
    unsigned bits = __float_as_uint(f);
    bits += 0x7FFF + ((bits >> 16) & 1);          // RNE
    return (unsigned short)(bits >> 16);
}

// ---------------------------------------------------------------- part1: LDS binning + fixed-CAP flush + staging
// r4-verbatim (proven <45us; NO global atomics -- r12's dense-flush convoy
// reverted). Counts written transposed for the fused consumer's coalesced read.
__global__ __launch_bounds__(1024) void part1(
    const float* __restrict__ x, const float* __restrict__ rel_W,
    const float* __restrict__ root_W, const int* __restrict__ row,
    const int* __restrict__ col,
    unsigned short* __restrict__ ab, unsigned short* __restrict__ Wb,
    int* __restrict__ cntMatT, unsigned* __restrict__ edgesF)
{
    __shared__ unsigned eL[NB1 * CAP];            // 75.3 KB
    __shared__ int cntL[NB1];
    const int tid = threadIdx.x;
    const int blk = blockIdx.x;

    for (int k = tid; k < NB1; k += 1024) cntL[k] = 0;
    __syncthreads();

    const int base = blk * CHUNK1;
    #pragma unroll
    for (int it = 0; it < CHUNK1 / 1024; ++it) {
        int e = base + it * 1024 + tid;
        if (e < N_EDGES) {
            int d = col[e];
            int bk = d >> 9;
            int r = atomicAdd(&cntL[bk], 1);
            if (r < CAP) eL[bk * CAP + r] = ((unsigned)(d & 511) << 17) | (unsigned)row[e];
        }
    }
    __syncthreads();

    for (int k = tid; k < NB1; k += 1024)         // transposed: consumer reads row wnd contiguously
        cntMatT[k * NBLK1 + blk] = min(cntL[k], CAP);

    const int wv = tid >> 6, lane = tid & 63;     // flush to fixed per-(block,window) regions
    for (int bk = wv; bk < NB1; bk += 16) {
        int c = min(cntL[bk], CAP);
        unsigned* dst = edgesF + ((size_t)blk * NB1 + bk) * CAP;
        for (int i = lane; i < c; i += 64) dst[i] = eL[bk * CAP + i];
    }

    // ---- staging x -> ab (bf16, 64-wide rows), grid-stride
    const int gt = blk * 1024 + tid;
    for (int t = gt; t < N_NODES * 8; t += NBLK1 * 1024) {
        int nrow = t >> 3, g = t & 7;
        const float4* xf = (const float4*)(x + (size_t)nrow * D + g * 8);
        float4 a = xf[0], b = xf[1];
        unsigned short u[8];
        u[0] = f2bf(a.x); u[1] = f2bf(a.y); u[2] = f2bf(a.z); u[3] = f2bf(a.w);
        u[4] = f2bf(b.x); u[5] = f2bf(b.y); u[6] = f2bf(b.z); u[7] = f2bf(b.w);
        *reinterpret_cast<uint4*>(ab + (size_t)nrow * XROW + g * 8) =
            *reinterpret_cast<const uint4*>(u);
    }
    if (gt < 1024) {                              // Wb row j = [rel_W j | root_W j]
        int j = gt >> 4, g = gt & 15;
        const float* src = (g < 8) ? (rel_W + j * 64 + g * 8) : (root_W + j * 64 + (g - 8) * 8);
        unsigned short u[8];
        #pragma unroll
        for (int i = 0; i < 8; ++i) u[i] = f2bf(src[i]);
        *reinterpret_cast<uint4*>(Wb + j * WROW + g * 8) = *reinterpret_cast<const uint4*>(u);
    }
}

// ---------------------------------------------------------------- fused: filter -> LDS ranks -> gather -> GEMM -> out
// 3125 blocks x 256 threads, 32 nodes each (exact). The ONE rank-assignment
// pass happens here, in LDS (r12 showed every rank pass costs ~45us when its
// state is global-backed; LDS-resident + fused kills part2's pass and the
// 25.6MB edge_src round-trip). Filter loop = r6-proven; paired gather (8 loads
// in flight) = r9-proven; GEMM = r7/r9-proven. XCD swizzle (m204 bijective)
// co-locates a window's 16 sibling blocks for L2 reuse of its ~75KB of runs.
__global__ __launch_bounds__(256) void fused(
    const unsigned short* __restrict__ ab, const unsigned* __restrict__ edgesF,
    const int* __restrict__ cntMatT, const float* __restrict__ adj_norm,
    const unsigned short* __restrict__ Wb, const float* __restrict__ root_b,
    float* __restrict__ out)
{
    __shared__ int eLs[32 * SLOTN];               // 8 KB: per-node slot lists
    __shared__ unsigned short a_sh[32 * ASH];     // 4.6 KB
    __shared__ int cnt[32];
    const int tid = threadIdx.x;

    // bijective XCD swizzle (m204): NWG = 8*390 + 5
    const int qq = NWG >> 3, rr = NWG & 7;        // 390, 5
    const int o = blockIdx.x, xcd = o & 7;
    const int b = (xcd < rr ? xcd * (qq + 1) : rr * (qq + 1) + (xcd - rr) * qq) + (o >> 3);

    const int wv = tid >> 6, lane = tid & 63;
    const int q = lane >> 4, sub = lane & 15;
    const int n0 = b * 32;
    const int wnd = b >> 4, grp = b & 15;         // window, 32-node group within it

    if (tid < 32) cnt[tid] = 0;
    __syncthreads();

    // ---- filter the window's runs; scatter matches into per-node LDS slots
    for (int sb = wv; sb < NBLK1; sb += 4) {
        int c = cntMatT[wnd * NBLK1 + sb];
        const unsigned* __restrict__ src = edgesF + ((size_t)sb * NB1 + wnd) * CAP;
        for (int i = lane; i < c; i += 64) {
            unsigned e = src[i];
            int dl = (int)(e >> 17);              // 0..511 within window
            if ((dl >> 5) == grp) {
                int ln = dl & 31;
                int r = atomicAdd(&cnt[ln], 1);
                if (r < SLOTN) eLs[ln * SLOTN + r] = (int)(e & 0x1FFFF);
            }
        }
    }
    __syncthreads();

    // ---- paired gather (r9 core): wave wv -> local nodes [wv*8, wv*8+8) as 4 pairs
    const unsigned short* __restrict__ xh = ab + sub * 4;

    for (int p = 0; p < 4; ++p) {
        const int lnA = wv * 8 + p * 2, lnB = lnA + 1;
        const int gnA = n0 + lnA, gnB = n0 + lnB;
        int dgA = cnt[lnA]; if (dgA > SLOTN) dgA = SLOTN;
        int dgB = cnt[lnB]; if (dgB > SLOTN) dgB = SLOTN;

        float a0A = 0.f, a1A = 0.f, a2A = 0.f, a3A = 0.f;
        float a0B = 0.f, a1B = 0.f, a2B = 0.f, a3B = 0.f;
        int idxA = (lane < dgA) ? eLs[lnA * SLOTN + lane] : 0;
        int idxB = (lane < dgB) ? eLs[lnB * SLOTN + lane] : 0;

        const int dgM = dgA > dgB ? dgA : dgB;
        for (int eb = 0; eb < dgM; eb += 16) {    // guarded 16-edge step per node
            const int e = eb + q;
            bool kA0 = e < dgA, kA1 = e + 4 < dgA, kA2 = e + 8 < dgA, kA3 = e + 12 < dgA;
            bool kB0 = e < dgB, kB1 = e + 4 < dgB, kB2 = e + 8 < dgB, kB3 = e + 12 < dgB;
            int iA0 = __shfl(idxA, e);      int iA1 = __shfl(idxA, e + 4);
            int iA2 = __shfl(idxA, e + 8);  int iA3 = __shfl(idxA, e + 12);
            int iB0 = __shfl(idxB, e);      int iB1 = __shfl(idxB, e + 4);
            int iB2 = __shfl(idxB, e + 8);  int iB3 = __shfl(idxB, e + 12);
            uint2 uA0 = *reinterpret_cast<const uint2*>(xh + (size_t)iA0 * XROW);
            uint2 uA1 = *reinterpret_cast<const uint2*>(xh + (size_t)iA1 * XROW);
            uint2 uA2 = *reinterpret_cast<const uint2*>(xh + (size_t)iA2 * XROW);
            uint2 uA3 = *reinterpret_cast<const uint2*>(xh + (size_t)iA3 * XROW);
            uint2 uB0 = *reinterpret_cast<const uint2*>(xh + (size_t)iB0 * XROW);
            uint2 uB1 = *reinterpret_cast<const uint2*>(xh + (size_t)iB1 * XROW);
            uint2 uB2 = *reinterpret_cast<const uint2*>(xh + (size_t)iB2 * XROW);
            uint2 uB3 = *reinterpret_cast<const uint2*>(xh + (size_t)iB3 * XROW);
            if (!kA0) { uA0.x = 0u; uA0.y = 0u; }
            if (!kA1) { uA1.x = 0u; uA1.y = 0u; }
            if (!kA2) { uA2.x = 0u; uA2.y = 0u; }
            if (!kA3) { uA3.x = 0u; uA3.y = 0u; }
            if (!kB0) { uB0.x = 0u; uB0.y = 0u; }
            if (!kB1) { uB1.x = 0u; uB1.y = 0u; }
            if (!kB2) { uB2.x = 0u; uB2.y = 0u; }
            if (!kB3) { uB3.x = 0u; uB3.y = 0u; }
            a0A += __uint_as_float(uA0.x << 16) + __uint_as_float(uA1.x << 16)
                 + __uint_as_float(uA2.x << 16) + __uint_as_float(uA3.x << 16);
            a1A += __uint_as_float(uA0.x & 0xffff0000u) + __uint_as_float(uA1.x & 0xffff0000u)
                 + __uint_as_float(uA2.x & 0xffff0000u) + __uint_as_float(uA3.x & 0xffff0000u);
            a2A += __uint_as_float(uA0.y << 16) + __uint_as_float(uA1.y << 16)
                 + __uint_as_float(uA2.y << 16) + __uint_as_float(uA3.y << 16);
            a3A += __uint_as_float(uA0.y & 0xffff0000u) + __uint_as_float(uA1.y & 0xffff0000u)
                 + __uint_as_float(uA2.y & 0xffff0000u) + __uint_as_float(uA3.y & 0xffff0000u);
            a0B += __uint_as_float(uB0.x << 16) + __uint_as_float(uB1.x << 16)
                 + __uint_as_float(uB2.x << 16) + __uint_as_float(uB3.x << 16);
            a1B += __uint_as_float(uB0.x & 0xffff0000u) + __uint_as_float(uB1.x & 0xffff0000u)
                 + __uint_as_float(uB2.x & 0xffff0000u) + __uint_as_float(uB3.x & 0xffff0000u);
            a2B += __uint_as_float(uB0.y << 16) + __uint_as_float(uB1.y << 16)
                 + __uint_as_float(uB2.y << 16) + __uint_as_float(uB3.y << 16);
            a3B += __uint_as_float(uB0.y & 0xffff0000u) + __uint_as_float(uB1.y & 0xffff0000u)
                 + __uint_as_float(uB2.y & 0xffff0000u) + __uint_as_float(uB3.y & 0xffff0000u);
        }

        a0A += __shfl_xor(a0A, 16, 64); a0A += __shfl_xor(a0A, 32, 64);
        a1A += __shfl_xor(a1A, 16, 64); a1A += __shfl_xor(a1A, 32, 64);
        a2A += __shfl_xor(a2A, 16, 64); a2A += __shfl_xor(a2A, 32, 64);
        a3A += __shfl_xor(a3A, 16, 64); a3A += __shfl_xor(a3A, 32, 64);
        a0B += __shfl_xor(a0B, 16, 64); a0B += __shfl_xor(a0B, 32, 64);
        a1B += __shfl_xor(a1B, 16, 64); a1B += __shfl_xor(a1B, 32, 64);
        a2B += __shfl_xor(a2B, 16, 64); a2B += __shfl_xor(a2B, 32, 64);
        a3B += __shfl_xor(a3B, 16, 64); a3B += __shfl_xor(a3B, 32, 64);

        if (q == 0) {                             // lane sub writes node A from own regs
            float invA = 1.0f / adj_norm[gnA];
            uint2 pA;
            pA.x = (unsigned)f2bf(a0A * invA) | ((unsigned)f2bf(a1A * invA) << 16);
            pA.y = (unsigned)f2bf(a2A * invA) | ((unsigned)f2bf(a3A * invA) << 16);
            *reinterpret_cast<uint2*>(a_sh + lnA * ASH + sub * 4) = pA;
        } else if (q == 1) {                      // lane 16+sub writes node B from own regs
            float invB = 1.0f / adj_norm[gnB];
            uint2 pB;
            pB.x = (unsigned)f2bf(a0B * invB) | ((unsigned)f2bf(a1B * invB) << 16);
            pB.y = (unsigned)f2bf(a2B * invB) | ((unsigned)f2bf(a3B * invB) << 16);
            *reinterpret_cast<uint2*>(a_sh + lnB * ASH + sub * 4) = pB;
        }
    }
    __syncthreads();

    // ---- GEMM 32x64x128: wave wv -> M-tile (wv>>1), N-tiles {(wv&1)*2, +1}
    const int mt = wv >> 1;
    const int arow = mt * 16 + sub;
    const int gnr = n0 + arow;                    // always < N_NODES (exact division)
    bf16x8 afrag[4];
    afrag[0] = *reinterpret_cast<const bf16x8*>(a_sh + arow * ASH + q * 8);
    afrag[1] = *reinterpret_cast<const bf16x8*>(a_sh + arow * ASH + q * 8 + 32);
    afrag[2] = *reinterpret_cast<const bf16x8*>(ab + (size_t)gnr * XROW + q * 8);
    afrag[3] = *reinterpret_cast<const bf16x8*>(ab + (size_t)gnr * XROW + q * 8 + 32);

    #pragma unroll
    for (int tt = 0; tt < 2; ++tt) {
        const int nt = (wv & 1) * 2 + tt;
        f32x4 acc = {0.f, 0.f, 0.f, 0.f};
        #pragma unroll
        for (int kk = 0; kk < 4; ++kk) {
            bf16x8 bfrag = *reinterpret_cast<const bf16x8*>(
                Wb + (nt * 16 + sub) * WROW + q * 8 + kk * 32);
            acc = __builtin_amdgcn_mfma_f32_16x16x32_bf16(afrag[kk], bfrag, acc, 0, 0, 0);
        }
        const int j = nt * 16 + sub;
        const float bias = root_b[j];
        #pragma unroll
        for (int r = 0; r < 4; ++r) {
            int node = n0 + mt * 16 + q * 4 + r;
            out[(size_t)node * D + j] = fmaxf(acc[r] + bias, 0.0f);
        }
    }
}

// ---------------------------------------------------------------- launch (2 dispatches, no memset)
extern "C" void kernel_launch(void* const* d_in, const int* in_sizes, int n_in,
                              void* d_out, int out_size, void* d_ws, size_t ws_size,
                              hipStream_t stream)
{
    const float* x        = (const float*)d_in[0];
    const int*   row      = (const int*)d_in[1];
    const int*   col      = (const int*)d_in[2];
    const float* adj_norm = (const float*)d_in[4];
    const float* root_W   = (const float*)d_in[5];
    const float* root_b   = (const float*)d_in[6];
    const float* rel_W    = (const float*)d_in[7];
    float* out = (float*)d_out;

    char* ws = (char*)d_ws;
    unsigned short* ab = (unsigned short*)ws;  ws += (size_t)N_NODES * XROW * 2;   // 12.8 MB
    unsigned short* Wb = (unsigned short*)ws;  ws += 64 * WROW * 2;                // 16 KB
    int* cntMatT       = (int*)ws;             ws += (size_t)NBLK1 * NB1 * 4;      // 154 KB
    unsigned* edgesF   = (unsigned*)ws;                                            // 14.8 MB

    part1<<<NBLK1, 1024, 0, stream>>>(x, rel_W, root_W, row, col, ab, Wb, cntMatT, edgesF);
    fused<<<NWG, 256, 0, stream>>>(ab, edgesF, cntMatT, adj_norm, Wb, root_b, out);
}